// Round 3
// baseline (223.399 us; speedup 1.0000x reference)
//
#include <hip/hip_runtime.h>

// CostTokenizer R9: hide the remaining latency (T14 prefetch + 5 blocks/CU).
//   Post-mortem R8: 72 us, VALU 37%, LDS ~37%, HBM 25% -> no pipe saturated,
//   still latency-bound. Exposed chains: (1) phase-1 per-chunk global gather
//   (~800 cy) serialized ahead of FMA by `unroll 1`; (2) phase-3 per-k s_load
//   weight row with no ILP. Occupancy 31% was ALSO capped by bounds(256,4)
//   (LDS 25KB allows 6 blocks, grid offers 5.25).
//   Fixes:
//   - T14 async-stage: prefetch next chunk's f2-gather (4xfloat4) + f1 quad
//     into regs BEFORE current chunk's FMA loop; commit to LDS at loop head.
//     Global latency hides under ~780 cy of FMA+ds_read. (+~20 VGPR, safe.)
//   - __launch_bounds__(256,5): 5 blocks/CU = 20 waves (VGPR ~90 <= 102).
//   - phase-3 `unroll 2`: two k-iters of s_load row + LDS reads in flight.
//   Spill alarm: WRITE_SIZE must stay exactly 64,512 KB.
//  - R6 rule kept: every loop indexing a register array is fully unrolled;
//    `unroll 1` only on loops touching LDS/global alone (scratch-spill trap).
//  - bank conflicts 5.6M are ~free 2-way aliasing (m136); phase-1 b128 reads
//    are conflict-free within 8-lane groups ((tx+2ty)&7 uniform).
//  - LDS union (reduce slices alias dead halos, 25.1 KB) + XCD column swizzle.
//
//  corr[k] = sum_c f1[c,h,w] * f2[c, (h-dy)%H, (w-dx)%W], k = (dy+3)*7 + (dx+3)
//  tok[t,b,d,h,w] = b[d] + (1/sqrt(C)) * sum_k corr[k] * w[k,d]

#define TD 192
#define HSTRIDE 26   // halo row stride in float4

template<int C, int H, int W, int TX, int TY>
__device__ __forceinline__ void level_tile(
    const float* __restrict__ lvl, const float* __restrict__ wm,
    const float* __restrict__ bias, float* __restrict__ out,
    int r, float scale, float* __restrict__ smem)
{
    const int HW = H * W;
    // XCD column-affinity: tiles of one column (pair,tX) are == mod 8 in bid
    const int xcd = r & 7, q = r >> 3;
    const int tY  = q % TY;
    const int col = (q / TY) * 8 + xcd;      // [0, 4*TX)
    const int pair = col / TX, tX = col % TX;

    const int t  = pair >> 1, bb = pair & 1;
    const float* f1 = lvl + (t * 2 + bb) * C * HW;
    const float* f2 = lvl + ((t + 1) * 2 + bb) * C * HW;

    const int tid  = threadIdx.x;
    const int lane = tid & 63;
    const int g    = tid >> 6;               // wave: channel group / d group
    const int tx   = lane & 15, ty = lane >> 4;   // lane owns row y0+ty
    const int x0   = tX * 16, y0 = tY * 4;
    const int x    = x0 + tx;
    const int y    = y0 + ty;

    float4* h = (float4*)smem + g * (10 * HSTRIDE);  // wave halo: 10 rows

    // staging offsets for halo cells p in [0,220): row=p/22, col=p%22
    int goff[4], loff[4];
#pragma unroll
    for (int i = 0; i < 4; ++i) {
        int p = lane + i * 64;
        int rr = p / 22, cc = p - rr * 22;
        int gy = y0 - 3 + rr; if (gy < 0) gy += H; if (gy >= H) gy -= H;
        int gx = x0 - 3 + cc; if (gx < 0) gx += W; if (gx >= W) gx -= W;
        goff[i] = gy * W + gx;
        loff[i] = rr * HSTRIDE + cc;
    }

    float acc[49];
#pragma unroll
    for (int k = 0; k < 49; ++k) acc[k] = 0.f;

    // ---- phase 1: correlation, wave-synchronous (wave-private halo) ----
    const int NCH = C / 16;                  // 4-channel chunks per wave
    const float* f2c = f2 + g * (C / 4) * HW;
    const float* f1c = f1 + g * (C / 4) * HW + y * W + x;

    float4 pv[4], pa;                        // register-staged next chunk
#pragma unroll
    for (int i = 0; i < 4; ++i) {            // prologue: gather chunk 0
        const float* s = f2c + goff[i];
        pv[i].x = s[0]; pv[i].y = s[HW]; pv[i].z = s[2 * HW]; pv[i].w = s[3 * HW];
    }
    pa.x = f1c[0]; pa.y = f1c[HW]; pa.z = f1c[2 * HW]; pa.w = f1c[3 * HW];

#pragma unroll 1
    for (int cg = 0; cg < NCH; ++cg) {       // body touches LDS/global only via
        // commit staged halo to LDS (wave-private; same-wave order is safe)
#pragma unroll                               // fully-unrolled inner loops
        for (int i = 0; i < 4; ++i)
            if (i < 3 || lane < 28) h[loff[i]] = pv[i];
        float a0 = pa.x, a1 = pa.y, a2 = pa.z, a3 = pa.w;
        f2c += 4 * HW; f1c += 4 * HW;
        if (cg + 1 < NCH) {                  // issue NEXT chunk's gathers now:
#pragma unroll                               // latency hides under FMA below
            for (int i = 0; i < 4; ++i) {
                const float* s = f2c + goff[i];
                pv[i].x = s[0]; pv[i].y = s[HW]; pv[i].z = s[2 * HW]; pv[i].w = s[3 * HW];
            }
            pa.x = f1c[0]; pa.y = f1c[HW]; pa.z = f1c[2 * HW]; pa.w = f1c[3 * HW];
        }
        // same-wave LDS RAW: compiler lgkmcnt waits cover it
#pragma unroll
        for (int b = 0; b < 7; ++b) {        // FULL unroll: indexes acc
            const float4* hp = h + ty * HSTRIDE + (tx + 6 - b);
#pragma unroll
            for (int a = 0; a < 7; ++a) {
                float4 lo = hp[(6 - a) * HSTRIDE];
                float s0 = acc[a * 7 + b];
                s0 = fmaf(a0, lo.x, s0); s0 = fmaf(a1, lo.y, s0);
                s0 = fmaf(a2, lo.z, s0); s0 = fmaf(a3, lo.w, s0);
                acc[a * 7 + b] = s0;
            }
        }
    }

    // ---- phase 2: cross-wave reduce; slices alias dead halo space ----
    __syncthreads();                         // all waves done with halos
    float* s0p = smem;                       // [49][64]
    float* s1p = smem + 49 * 64;
    if (g >= 2) {
        float* dst = (g == 2) ? s0p : s1p;
#pragma unroll
        for (int k = 0; k < 49; ++k)         // FULL unroll: indexes acc
            dst[k * 64 + lane] = acc[k];
    }
    __syncthreads();
    if (g < 2) {
        float* dst = (g == 0) ? s0p : s1p;
#pragma unroll
        for (int k = 0; k < 49; ++k)         // FULL unroll: indexes acc
            dst[k * 64 + lane] += acc[k];
    }
    __syncthreads();

    // ---- phase 3: 49 -> 192, wave g owns d in [48g, 48g+48), 1 px/lane ----
    const int dbase = __builtin_amdgcn_readfirstlane(g * 48);
    float sA[48];
#pragma unroll
    for (int j = 0; j < 48; ++j) sA[j] = bias[dbase + j];
#pragma unroll 2
    for (int k = 0; k < 49; ++k) {           // unroll 2: two w-rows in flight
        float c0 = (s0p[k * 64 + lane] + s1p[k * 64 + lane]) * scale;
        const float* wr = wm + k * TD + dbase;   // wave-uniform -> s_load
#pragma unroll
        for (int j = 0; j < 48; ++j)         // FULL unroll: indexes sA
            sA[j] = fmaf(wr[j], c0, sA[j]);
    }
    float* op = out + (pair * TD + dbase) * HW + y * W + x;
#pragma unroll
    for (int j = 0; j < 48; ++j)             // FULL unroll: indexes sA
        op[j * HW] = sA[j];
}

__global__ __launch_bounds__(256, 5)
void cost_tokenizer(const float* __restrict__ l1, const float* __restrict__ l2,
                    const float* __restrict__ l3,
                    const float* __restrict__ w1, const float* __restrict__ b1,
                    const float* __restrict__ w2, const float* __restrict__ b2,
                    const float* __restrict__ w3, const float* __restrict__ b3,
                    float* __restrict__ out)
{
    __shared__ __align__(16) float smem[6272];  // max(2*49*64, 4*10*26*4) f = 25.1 KB
    int bid = blockIdx.x;
    // heavy levels first: L3 (12 chunks/wave), L2 (8), L1 (4)
    if (bid < 64) {
        level_tile<192, 32, 32, 2, 8>(l3, w3, b3, out + 15728640,
                                      bid, 0.072168783648703216f, smem);
    } else if (bid < 320) {
        level_tile<128, 64, 64, 4, 16>(l2, w2, b2, out + 12582912,
                                       bid - 64, 0.088388347648318447f, smem);
    } else {
        level_tile<64, 128, 128, 8, 32>(l1, w1, b1, out,
                                        bid - 320, 0.125f, smem);
    }
}

extern "C" void kernel_launch(void* const* d_in, const int* in_sizes, int n_in,
                              void* d_out, int out_size, void* d_ws, size_t ws_size,
                              hipStream_t stream)
{
    const float* l1 = (const float*)d_in[0];
    const float* l2 = (const float*)d_in[1];
    const float* l3 = (const float*)d_in[2];
    const float* w1 = (const float*)d_in[3];
    const float* b1 = (const float*)d_in[4];
    const float* w2 = (const float*)d_in[5];
    const float* b2 = (const float*)d_in[6];
    const float* w3 = (const float*)d_in[7];
    const float* b3 = (const float*)d_in[8];
    float* out = (float*)d_out;

    hipLaunchKernelGGL(cost_tokenizer, dim3(1344), dim3(256), 0, stream,
                       l1, l2, l3, w1, b1, w2, b2, w3, b3, out);
}

// Round 4
// 171.787 us; speedup vs baseline: 1.3004x; 1.3004x over previous
//
#include <hip/hip_runtime.h>

// CostTokenizer R10: revert the spill, keep the prefetch.
//   Post-mortem R9: __launch_bounds__(256,5) forced VGPR 64->48 (HW wave-slot
//   quantum steps at 64/128 — 5 waves/SIMD needs <=~64 VGPR), acc[49] went
//   to SCRATCH: WRITE_SIZE 64.5->95.9 MB, FETCH +33 MB, dur 72->150 us.
//   RULE: with 256-thread blocks and >=49 floats/lane live, never request
//   more than 4 waves/EU in launch_bounds.
//   R10 = R9's T14 prefetch + phase-3 unroll-2, at __launch_bounds__(256,4)
//   (128-VGPR budget; live state ~95 regs fits). Clean A/B vs R8 (72 us).
//   Spill gate: WRITE_SIZE must be exactly 64,512 KB.
//  - R6 rule kept: every loop indexing a register array is fully unrolled;
//    `unroll 1` only on loops touching LDS/global alone (scratch-spill trap).
//  - bank conflicts 5.6M are ~free 2-way aliasing (m136); phase-1 b128 reads
//    are conflict-free within 8-lane groups ((tx+2ty)&7 uniform).
//  - LDS union (reduce slices alias dead halos, 25.1 KB) + XCD column swizzle.
//
//  corr[k] = sum_c f1[c,h,w] * f2[c, (h-dy)%H, (w-dx)%W], k = (dy+3)*7 + (dx+3)
//  tok[t,b,d,h,w] = b[d] + (1/sqrt(C)) * sum_k corr[k] * w[k,d]

#define TD 192
#define HSTRIDE 26   // halo row stride in float4

template<int C, int H, int W, int TX, int TY>
__device__ __forceinline__ void level_tile(
    const float* __restrict__ lvl, const float* __restrict__ wm,
    const float* __restrict__ bias, float* __restrict__ out,
    int r, float scale, float* __restrict__ smem)
{
    const int HW = H * W;
    // XCD column-affinity: tiles of one column (pair,tX) are == mod 8 in bid
    const int xcd = r & 7, q = r >> 3;
    const int tY  = q % TY;
    const int col = (q / TY) * 8 + xcd;      // [0, 4*TX)
    const int pair = col / TX, tX = col % TX;

    const int t  = pair >> 1, bb = pair & 1;
    const float* f1 = lvl + (t * 2 + bb) * C * HW;
    const float* f2 = lvl + ((t + 1) * 2 + bb) * C * HW;

    const int tid  = threadIdx.x;
    const int lane = tid & 63;
    const int g    = tid >> 6;               // wave: channel group / d group
    const int tx   = lane & 15, ty = lane >> 4;   // lane owns row y0+ty
    const int x0   = tX * 16, y0 = tY * 4;
    const int x    = x0 + tx;
    const int y    = y0 + ty;

    float4* h = (float4*)smem + g * (10 * HSTRIDE);  // wave halo: 10 rows

    // staging offsets for halo cells p in [0,220): row=p/22, col=p%22
    int goff[4], loff[4];
#pragma unroll
    for (int i = 0; i < 4; ++i) {
        int p = lane + i * 64;
        int rr = p / 22, cc = p - rr * 22;
        int gy = y0 - 3 + rr; if (gy < 0) gy += H; if (gy >= H) gy -= H;
        int gx = x0 - 3 + cc; if (gx < 0) gx += W; if (gx >= W) gx -= W;
        goff[i] = gy * W + gx;
        loff[i] = rr * HSTRIDE + cc;
    }

    float acc[49];
#pragma unroll
    for (int k = 0; k < 49; ++k) acc[k] = 0.f;

    // ---- phase 1: correlation, wave-synchronous (wave-private halo) ----
    const int NCH = C / 16;                  // 4-channel chunks per wave
    const float* f2c = f2 + g * (C / 4) * HW;
    const float* f1c = f1 + g * (C / 4) * HW + y * W + x;

    float4 pv[4], pa;                        // register-staged next chunk
#pragma unroll
    for (int i = 0; i < 4; ++i) {            // prologue: gather chunk 0
        const float* s = f2c + goff[i];
        pv[i].x = s[0]; pv[i].y = s[HW]; pv[i].z = s[2 * HW]; pv[i].w = s[3 * HW];
    }
    pa.x = f1c[0]; pa.y = f1c[HW]; pa.z = f1c[2 * HW]; pa.w = f1c[3 * HW];

#pragma unroll 1
    for (int cg = 0; cg < NCH; ++cg) {       // body touches LDS/global only via
        // commit staged halo to LDS (wave-private; same-wave order is safe)
#pragma unroll                               // fully-unrolled inner loops
        for (int i = 0; i < 4; ++i)
            if (i < 3 || lane < 28) h[loff[i]] = pv[i];
        float a0 = pa.x, a1 = pa.y, a2 = pa.z, a3 = pa.w;
        f2c += 4 * HW; f1c += 4 * HW;
        if (cg + 1 < NCH) {                  // issue NEXT chunk's gathers now:
#pragma unroll                               // latency hides under FMA below
            for (int i = 0; i < 4; ++i) {
                const float* s = f2c + goff[i];
                pv[i].x = s[0]; pv[i].y = s[HW]; pv[i].z = s[2 * HW]; pv[i].w = s[3 * HW];
            }
            pa.x = f1c[0]; pa.y = f1c[HW]; pa.z = f1c[2 * HW]; pa.w = f1c[3 * HW];
        }
        // same-wave LDS RAW: compiler lgkmcnt waits cover it
#pragma unroll
        for (int b = 0; b < 7; ++b) {        // FULL unroll: indexes acc
            const float4* hp = h + ty * HSTRIDE + (tx + 6 - b);
#pragma unroll
            for (int a = 0; a < 7; ++a) {
                float4 lo = hp[(6 - a) * HSTRIDE];
                float s0 = acc[a * 7 + b];
                s0 = fmaf(a0, lo.x, s0); s0 = fmaf(a1, lo.y, s0);
                s0 = fmaf(a2, lo.z, s0); s0 = fmaf(a3, lo.w, s0);
                acc[a * 7 + b] = s0;
            }
        }
    }

    // ---- phase 2: cross-wave reduce; slices alias dead halo space ----
    __syncthreads();                         // all waves done with halos
    float* s0p = smem;                       // [49][64]
    float* s1p = smem + 49 * 64;
    if (g >= 2) {
        float* dst = (g == 2) ? s0p : s1p;
#pragma unroll
        for (int k = 0; k < 49; ++k)         // FULL unroll: indexes acc
            dst[k * 64 + lane] = acc[k];
    }
    __syncthreads();
    if (g < 2) {
        float* dst = (g == 0) ? s0p : s1p;
#pragma unroll
        for (int k = 0; k < 49; ++k)         // FULL unroll: indexes acc
            dst[k * 64 + lane] += acc[k];
    }
    __syncthreads();

    // ---- phase 3: 49 -> 192, wave g owns d in [48g, 48g+48), 1 px/lane ----
    const int dbase = __builtin_amdgcn_readfirstlane(g * 48);
    float sA[48];
#pragma unroll
    for (int j = 0; j < 48; ++j) sA[j] = bias[dbase + j];
#pragma unroll 2
    for (int k = 0; k < 49; ++k) {           // unroll 2: two w-rows in flight
        float c0 = (s0p[k * 64 + lane] + s1p[k * 64 + lane]) * scale;
        const float* wr = wm + k * TD + dbase;   // wave-uniform -> s_load
#pragma unroll
        for (int j = 0; j < 48; ++j)         // FULL unroll: indexes sA
            sA[j] = fmaf(wr[j], c0, sA[j]);
    }
    float* op = out + (pair * TD + dbase) * HW + y * W + x;
#pragma unroll
    for (int j = 0; j < 48; ++j)             // FULL unroll: indexes sA
        op[j * HW] = sA[j];
}

__global__ __launch_bounds__(256, 4)
void cost_tokenizer(const float* __restrict__ l1, const float* __restrict__ l2,
                    const float* __restrict__ l3,
                    const float* __restrict__ w1, const float* __restrict__ b1,
                    const float* __restrict__ w2, const float* __restrict__ b2,
                    const float* __restrict__ w3, const float* __restrict__ b3,
                    float* __restrict__ out)
{
    __shared__ __align__(16) float smem[6272];  // max(2*49*64, 4*10*26*4) f = 25.1 KB
    int bid = blockIdx.x;
    // heavy levels first: L3 (12 chunks/wave), L2 (8), L1 (4)
    if (bid < 64) {
        level_tile<192, 32, 32, 2, 8>(l3, w3, b3, out + 15728640,
                                      bid, 0.072168783648703216f, smem);
    } else if (bid < 320) {
        level_tile<128, 64, 64, 4, 16>(l2, w2, b2, out + 12582912,
                                       bid - 64, 0.088388347648318447f, smem);
    } else {
        level_tile<64, 128, 128, 8, 32>(l1, w1, b1, out,
                                        bid - 320, 0.125f, smem);
    }
}

extern "C" void kernel_launch(void* const* d_in, const int* in_sizes, int n_in,
                              void* d_out, int out_size, void* d_ws, size_t ws_size,
                              hipStream_t stream)
{
    const float* l1 = (const float*)d_in[0];
    const float* l2 = (const float*)d_in[1];
    const float* l3 = (const float*)d_in[2];
    const float* w1 = (const float*)d_in[3];
    const float* b1 = (const float*)d_in[4];
    const float* w2 = (const float*)d_in[5];
    const float* b2 = (const float*)d_in[6];
    const float* w3 = (const float*)d_in[7];
    const float* b3 = (const float*)d_in[8];
    float* out = (float*)d_out;

    hipLaunchKernelGGL(cost_tokenizer, dim3(1344), dim3(256), 0, stream,
                       l1, l2, l3, w1, b1, w2, b2, w3, b3, out);
}